// Round 1
// 253.880 us; speedup vs baseline: 1.1105x; 1.1105x over previous
//
#include <hip/hip_runtime.h>

#define TT 6
#define D 128
#define KTOT 896           // 6*128 means + 128 x-slab
#define BM 64
#define SCAN_BLK 2048
#define LN_EPS 1e-5f

typedef __bf16 bf16x8 __attribute__((ext_vector_type(8)));
typedef float f32x4 __attribute__((ext_vector_type(4)));

__device__ __forceinline__ unsigned short f2bf(float f) {
    unsigned int u = __float_as_uint(f);
    unsigned int r = (u + 0x7FFFu + ((u >> 16) & 1u)) >> 16;  // RNE
    return (unsigned short)r;
}
__device__ __forceinline__ float bflo(unsigned int v) { return __uint_as_float(v << 16); }
__device__ __forceinline__ float bfhi(unsigned int v) { return __uint_as_float(v & 0xffff0000u); }

// XOR-swizzled LDS offset (ushort elems) for 128-elem rows: 16 chunks of 8.
// Involution in the chunk index -> same formula maps slot->chunk and chunk->slot.
__device__ __forceinline__ int lds_off128(int row, int kgrp) {
    return row * 128 + (((kgrp & 7) ^ (row & 7)) | (kgrp & 8)) * 8;
}

// async global->LDS 16B copy; LDS dest is wave-uniform base + lane*16 (linear),
// swizzle is applied by pre-swizzling the per-lane GLOBAL source address.
__device__ __forceinline__ void g2lds16(const unsigned short* g, unsigned short* l) {
    __builtin_amdgcn_global_load_lds(
        (const __attribute__((address_space(1))) unsigned int*)g,
        (__attribute__((address_space(3))) unsigned int*)l,
        16, 0, 0);
}

// --- setup: cast x->xb, transpose weights to bf16 WlT, bias_total, + histogram ---
__global__ void setup_kernel(const float* __restrict__ x, const float* __restrict__ W_l,
                             const float* __restrict__ W_r, const float* __restrict__ b,
                             const float* __restrict__ emb,
                             const int* __restrict__ ei, const int* __restrict__ et,
                             unsigned short* __restrict__ xb, unsigned short* __restrict__ WlT,
                             float* __restrict__ bias_total, int* __restrict__ hist,
                             int total8, int E, int N) {
    int i = blockIdx.x * 256 + threadIdx.x;
    if (i < total8) {
        const float4* p = (const float4*)x + (size_t)i * 2;
        float4 a = p[0], bb = p[1];
        uint4 o;
        o.x = (unsigned int)f2bf(a.x) | ((unsigned int)f2bf(a.y) << 16);
        o.y = (unsigned int)f2bf(a.z) | ((unsigned int)f2bf(a.w) << 16);
        o.z = (unsigned int)f2bf(bb.x) | ((unsigned int)f2bf(bb.y) << 16);
        o.w = (unsigned int)f2bf(bb.z) | ((unsigned int)f2bf(bb.w) << 16);
        ((uint4*)xb)[i] = o;
        return;
    }
    i -= total8;
    if (i < 6 * D * D) {
        int t = i >> 14, rem = i & 16383, k = rem >> 7, n = rem & 127;
        WlT[n * KTOT + t * D + k] = f2bf(W_l[i]);
        return;
    }
    if (i < 7 * D * D) {
        int rem = i & 16383, k = rem >> 7, n = rem & 127;
        float s = 0.f;
#pragma unroll
        for (int tt = 0; tt < TT; ++tt) s += W_r[tt * D * D + rem];
        WlT[n * KTOT + TT * D + k] = f2bf(s);
        return;
    }
    if (i < 7 * D * D + D) {
        int o = i - 7 * D * D;
        float s = 0.f;
#pragma unroll
        for (int t = 0; t < TT; ++t) s += b[t * D + o] + emb[t * D + o];
        bias_total[o] = s;
        return;
    }
    i -= 7 * D * D + D;
    if (i < E) atomicAdd(&hist[et[i] * N + ei[E + i]], 1);
}

// --- single-dispatch exclusive scan (decoupled lookback, all-aggregate form) ---
__global__ void scan_kernel(const int* __restrict__ in, int* __restrict__ off,
                            int* __restrict__ cursor, int* __restrict__ agg,
                            int* __restrict__ flag, int S, int E) {
    __shared__ int wsum[4];
    __shared__ int woff[4];
    __shared__ int psum[4];
    __shared__ int s_prefix;
    int tid = threadIdx.x;
    int tile = blockIdx.x;
    int base = tile * SCAN_BLK + tid * 8;
    int v[8];
    int ts = 0;
#pragma unroll
    for (int j = 0; j < 8; ++j) {
        v[j] = (base + j < S) ? in[base + j] : 0;
        ts += v[j];
    }
    int lane = tid & 63, wave = tid >> 6;
    int inc = ts;
#pragma unroll
    for (int o = 1; o < 64; o <<= 1) {
        int n = __shfl_up(inc, o);
        if (lane >= o) inc += n;
    }
    if (lane == 63) wsum[wave] = inc;
    __syncthreads();
    if (tid == 0) {
        int r = 0;
#pragma unroll
        for (int w = 0; w < 4; ++w) { int t = wsum[w]; woff[w] = r; r += t; }
        agg[tile] = r;
        __threadfence();
        atomicExch(&flag[tile], 1);
    }
    int part = 0;
    for (int j = tid; j < tile; j += 256) {
        while (atomicAdd(&flag[j], 0) == 0) {}
        part += atomicAdd(&agg[j], 0);
    }
#pragma unroll
    for (int o = 32; o >= 1; o >>= 1) part += __shfl_down(part, o);
    if (lane == 0) psum[wave] = part;
    __syncthreads();
    if (tid == 0) s_prefix = psum[0] + psum[1] + psum[2] + psum[3];
    __syncthreads();
    int run = s_prefix + woff[wave] + inc - ts;
#pragma unroll
    for (int j = 0; j < 8; ++j) {
        if (base + j < S) { off[base + j] = run; cursor[base + j] = run; }
        run += v[j];
    }
    if (tile == 0 && tid == 0) off[S] = E;
}

__global__ void fill_kernel(const int* __restrict__ ei, const int* __restrict__ et,
                            int* __restrict__ cursor, int* __restrict__ sorted_src,
                            int E, int N) {
    int e = blockIdx.x * 256 + threadIdx.x;
    if (e >= E) return;
    int seg = et[e] * N + ei[E + e];
    int pos = atomicAdd(&cursor[seg], 1);
    sorted_src[pos] = ei[e];
}

// --- fused: prefetch-4 gather-mean -> bf16 MFMA -> bias+LN+ReLU ---
// BM=64, 256 threads, LDS 49.7KB -> 3 blocks/CU (12 waves/CU). B and x slabs
// staged async via global_load_lds (linear LDS dest, inverse-swizzled source).
__launch_bounds__(256, 3)
__global__ void fused_kernel(const unsigned short* __restrict__ xb,
                             const int* __restrict__ off, const int* __restrict__ sorted_src,
                             const unsigned short* __restrict__ WlT,
                             const float* __restrict__ bias_total,
                             const float* __restrict__ gamma, const float* __restrict__ beta,
                             float* __restrict__ out, int N) {
    __shared__ unsigned short As[BM * 128];   // 16 KB swizzled A slab [m][k]
    __shared__ unsigned short Bs[128 * 128];  // 32 KB swizzled B slab [n][k]
    __shared__ int offs[TT * (BM + 1)];       // block's CSR bounds, all slabs

    int tid = threadIdx.x;
    int lane = tid & 63, wave = tid >> 6;
    int q = lane >> 4, c16 = lane & 15;
    int qid = tid >> 4, l16 = tid & 15;       // 16 groups x 16 lanes
    int rl = lane >> 4;                       // row-within-chunk for async stage
    int blockRow = blockIdx.x * BM;

    for (int i = tid; i < TT * (BM + 1); i += 256) {
        int t = i / (BM + 1), r = i - t * (BM + 1);
        int g = blockRow + r; if (g > N) g = N;
        offs[i] = off[t * N + g];
    }

    f32x4 acc[8];
#pragma unroll
    for (int ct = 0; ct < 8; ++ct) acc[ct] = (f32x4){0.f, 0.f, 0.f, 0.f};

    __syncthreads();   // offs ready

#pragma unroll 1
    for (int t = 0; t < 7; ++t) {
        // async-stage B slab: 32 chunks of 1KB (4 rows each), source pre-swizzled
#pragma unroll
        for (int r = 0; r < 8; ++r) {
            int chunk = r * 4 + wave;              // 0..31
            int row = chunk * 4 + rl;              // 0..127
            int kg = ((l16 & 7) ^ (row & 7)) | (l16 & 8);
            g2lds16(WlT + (size_t)row * KTOT + t * D + kg * 8, Bs + chunk * 512);
        }

        if (t < TT) {
            // gather-mean: group of 16 lanes handles 4 rows, in 2 pairs,
            // prefetch-4 guarded loads per row (covers ~96% of edges)
#pragma unroll
            for (int pr = 0; pr < 2; ++pr) {
                int e0[2], cn[2];
#pragma unroll
                for (int i = 0; i < 2; ++i) {
                    int row = qid * 4 + pr * 2 + i;
                    int a = offs[t * (BM + 1) + row];
                    int bnd = offs[t * (BM + 1) + row + 1];
                    e0[i] = a;
                    cn[i] = (blockRow + row < N) ? (bnd - a) : 0;
                }
                int ix[2][4];
#pragma unroll
                for (int i = 0; i < 2; ++i)
#pragma unroll
                    for (int j = 0; j < 4; ++j) {
                        ix[i][j] = 0;
                        if (cn[i] > j) ix[i][j] = sorted_src[e0[i] + j];
                    }
                uint4 v[2][4];
#pragma unroll
                for (int i = 0; i < 2; ++i)
#pragma unroll
                    for (int j = 0; j < 4; ++j) {
                        v[i][j] = (uint4){0u, 0u, 0u, 0u};
                        if (cn[i] > j)
                            v[i][j] = *(const uint4*)(xb + (size_t)ix[i][j] * D + l16 * 8);
                    }
#pragma unroll
                for (int i = 0; i < 2; ++i) {
                    float a0 = bflo(v[i][0].x) + bflo(v[i][1].x) + bflo(v[i][2].x) + bflo(v[i][3].x);
                    float a1 = bfhi(v[i][0].x) + bfhi(v[i][1].x) + bfhi(v[i][2].x) + bfhi(v[i][3].x);
                    float a2 = bflo(v[i][0].y) + bflo(v[i][1].y) + bflo(v[i][2].y) + bflo(v[i][3].y);
                    float a3 = bfhi(v[i][0].y) + bfhi(v[i][1].y) + bfhi(v[i][2].y) + bfhi(v[i][3].y);
                    float a4 = bflo(v[i][0].z) + bflo(v[i][1].z) + bflo(v[i][2].z) + bflo(v[i][3].z);
                    float a5 = bfhi(v[i][0].z) + bfhi(v[i][1].z) + bfhi(v[i][2].z) + bfhi(v[i][3].z);
                    float a6 = bflo(v[i][0].w) + bflo(v[i][1].w) + bflo(v[i][2].w) + bflo(v[i][3].w);
                    float a7 = bfhi(v[i][0].w) + bfhi(v[i][1].w) + bfhi(v[i][2].w) + bfhi(v[i][3].w);
                    int e = e0[i] + 4, end = e0[i] + cn[i];
#pragma unroll 1
                    while (e < end) {
                        int s = sorted_src[e++];
                        uint4 vv = *(const uint4*)(xb + (size_t)s * D + l16 * 8);
                        a0 += bflo(vv.x); a1 += bfhi(vv.x);
                        a2 += bflo(vv.y); a3 += bfhi(vv.y);
                        a4 += bflo(vv.z); a5 += bfhi(vv.z);
                        a6 += bflo(vv.w); a7 += bfhi(vv.w);
                    }
                    if (cn[i] > 1) {
                        float sc = 1.f / (float)cn[i];
                        a0 *= sc; a1 *= sc; a2 *= sc; a3 *= sc;
                        a4 *= sc; a5 *= sc; a6 *= sc; a7 *= sc;
                    }
                    uint4 p;
                    p.x = (unsigned int)f2bf(a0) | ((unsigned int)f2bf(a1) << 16);
                    p.y = (unsigned int)f2bf(a2) | ((unsigned int)f2bf(a3) << 16);
                    p.z = (unsigned int)f2bf(a4) | ((unsigned int)f2bf(a5) << 16);
                    p.w = (unsigned int)f2bf(a6) | ((unsigned int)f2bf(a7) << 16);
                    *(uint4*)&As[lds_off128(qid * 4 + pr * 2 + i, l16)] = p;
                }
            }
        } else {
            // x-slab: async copy of this block's rows, source pre-swizzled
#pragma unroll
            for (int r = 0; r < 4; ++r) {
                int chunk = r * 4 + wave;              // 0..15
                int row = chunk * 4 + rl;              // 0..63
                int gr = blockRow + row; if (gr >= N) gr = N - 1;
                int kg = ((l16 & 7) ^ (row & 7)) | (l16 & 8);
                g2lds16(xb + (size_t)gr * D + kg * 8, As + chunk * 512);
            }
        }

        __syncthreads();   // As writes + async B/x drained (compiler vmcnt(0))

        // MFMA: K=128 in 4 steps of 32; wave owns 16 rows
#pragma unroll
        for (int ks = 0; ks < 4; ++ks) {
            int kgrp = ks * 4 + q;
            bf16x8 af = *(const bf16x8*)&As[lds_off128(wave * 16 + c16, kgrp)];
#pragma unroll
            for (int ct = 0; ct < 8; ++ct) {
                bf16x8 bfr = *(const bf16x8*)&Bs[lds_off128(ct * 16 + c16, kgrp)];
                acc[ct] = __builtin_amdgcn_mfma_f32_16x16x32_bf16(af, bfr, acc[ct], 0, 0, 0);
            }
        }
        __syncthreads();   // MFMA frag reads complete before next slab overwrites
    }

    // epilogue: bias + LayerNorm + ReLU
    float bias_c[8], g_c[8], bt_c[8];
#pragma unroll
    for (int ct = 0; ct < 8; ++ct) {
        int col = ct * 16 + c16;
        bias_c[ct] = bias_total[col];
        g_c[ct] = gamma[col];
        bt_c[ct] = beta[col];
    }
#pragma unroll
    for (int reg = 0; reg < 4; ++reg) {
        float h[8];
        float s = 0.f, s2 = 0.f;
#pragma unroll
        for (int ct = 0; ct < 8; ++ct) {
            h[ct] = acc[ct][reg] + bias_c[ct];
            s += h[ct];
            s2 += h[ct] * h[ct];
        }
#pragma unroll
        for (int o = 8; o >= 1; o >>= 1) {
            s  += __shfl_xor(s, o, 16);
            s2 += __shfl_xor(s2, o, 16);
        }
        float mu = s * (1.f / 128.f);
        float var = s2 * (1.f / 128.f) - mu * mu;
        float rstd = rsqrtf(var + LN_EPS);
        int row = blockRow + wave * 16 + q * 4 + reg;
        if (row < N) {
#pragma unroll
            for (int ct = 0; ct < 8; ++ct) {
                float y = (h[ct] - mu) * rstd * g_c[ct] + bt_c[ct];
                out[(size_t)row * D + ct * 16 + c16] = fmaxf(y, 0.f);
            }
        }
    }
}

extern "C" void kernel_launch(void* const* d_in, const int* in_sizes, int n_in,
                              void* d_out, int out_size, void* d_ws, size_t ws_size,
                              hipStream_t stream) {
    const float* x     = (const float*)d_in[0];
    const int*   ei    = (const int*)d_in[1];
    const int*   et    = (const int*)d_in[2];
    const float* W_l   = (const float*)d_in[3];
    const float* W_r   = (const float*)d_in[4];
    const float* b     = (const float*)d_in[5];
    const float* emb   = (const float*)d_in[6];
    const float* gamma = (const float*)d_in[7];
    const float* beta  = (const float*)d_in[8];

    int N = in_sizes[0] / D;
    int E = in_sizes[2];
    int S = N * TT;
    int NB = (S + SCAN_BLK - 1) / SCAN_BLK;
    int NBLK = (N + BM - 1) / BM;

    // workspace carve (hist+flag adjacent for a single memset)
    int* hist       = (int*)d_ws;            // S
    int* flag       = hist + S;              // NB
    int* off        = flag + NB;             // S+1
    int* cursor     = off + S + 1;           // S
    int* agg        = cursor + S;            // NB
    int* sorted_src = agg + NB;              // E
    size_t ofs = (size_t)((char*)(sorted_src + E) - (char*)d_ws);
    ofs = (ofs + 15) & ~(size_t)15;
    unsigned short* WlT = (unsigned short*)((char*)d_ws + ofs);   // 128*896
    float* bias_total = (float*)(WlT + D * KTOT);                 // 128
    size_t ofs2 = (size_t)((char*)(bias_total + D) - (char*)d_ws);
    ofs2 = (ofs2 + 15) & ~(size_t)15;
    unsigned short* xb = (unsigned short*)((char*)d_ws + ofs2);   // N*128 bf16

    hipMemsetAsync(hist, 0, (size_t)(S + NB) * sizeof(int), stream);

    int total8 = N * D / 8;
    int G = total8 + 7 * D * D + D + E;
    setup_kernel<<<(G + 255) / 256, 256, 0, stream>>>(x, W_l, W_r, b, emb, ei, et,
                                                      xb, WlT, bias_total, hist,
                                                      total8, E, N);

    scan_kernel<<<NB, 256, 0, stream>>>(hist, off, cursor, agg, flag, S, E);
    fill_kernel<<<(E + 255) / 256, 256, 0, stream>>>(ei, et, cursor, sorted_src, E, N);

    fused_kernel<<<NBLK, 256, 0, stream>>>(xb, off, sorted_src, WlT, bias_total,
                                           gamma, beta, (float*)d_out, N);
}